// Round 2
// baseline (107.301 us; speedup 1.0000x reference)
//
#include <hip/hip_runtime.h>

// TransformerBlockQuantum — analytic collapse of the qlayer:
// pre-CNOT state is a product of RX rotations => wire w has <Z> = cos(phi_w).
// CNOT ring (k -> k+1 mod 8) maps bits to prefix-XORs:
//   b_w = a_0 ^ ... ^ a_w  (w=1..7),  b_0 = a_1 ^ ... ^ a_7
// => out[w] = prod_{j<=w} cos(phi_j) (w>=1), out[0] = prod_{j=1..7} cos(phi_j)

__device__ __forceinline__ void zprod8(const float z[8], float out[8]) {
    float p = z[0];
#pragma unroll
    for (int w = 1; w < 8; ++w) { p *= z[w]; out[w] = p; }
    float q = z[1];
#pragma unroll
    for (int w = 2; w < 8; ++w) q *= z[w];
    out[0] = q;
}

// ---------------------------------------------------------------------------
// Kernel 1: fused qkv (attn qlayer) + 2-head dk=4 attention over T=512.
// grid.x = B*2*2 = 512 : blockIdx.x = ((b*2 + head)*2 + qhalf), 256 threads.
// Each block recomputes qkv for all 512 rows of (b, head) into LDS, then each
// thread handles one query row. |qkv| <= 1 => |score| <= 2 => no max pass.
// ctx written to `ctx` (= d_out staging) in (B,T,8) token layout.
// ---------------------------------------------------------------------------
__global__ __launch_bounds__(256) void k_attn(const float* __restrict__ x,
                                              const float* __restrict__ tha,
                                              float* __restrict__ ctx) {
    const int qt = blockIdx.x & 1;
    const int hh = (blockIdx.x >> 1) & 1;
    const int b  = blockIdx.x >> 2;
    const int tid = threadIdx.x;

    __shared__ float4 kvs[512];

    float th[8];
#pragma unroll
    for (int w = 0; w < 8; ++w) th[w] = tha[w];   // uniform -> scalar loads

    // stage K/V rows tid and tid+256 (recompute qlayer from x)
#pragma unroll
    for (int rr = 0; rr < 2; ++rr) {
        const int r = tid + rr * 256;
        const float4* xp = (const float4*)(x + ((size_t)b * 512 + r) * 8);
        const float4 a = xp[0];
        const float4 bb = xp[1];
        const float ang[8] = {a.x, a.y, a.z, a.w, bb.x, bb.y, bb.z, bb.w};
        float z[8], o[8];
#pragma unroll
        for (int w = 0; w < 8; ++w) z[w] = cosf(ang[w] + th[w]);
        zprod8(z, o);
        kvs[r] = hh ? make_float4(o[4], o[5], o[6], o[7])
                    : make_float4(o[0], o[1], o[2], o[3]);
    }
    __syncthreads();

    const int qrow = qt * 256 + tid;
    float4 qv = kvs[qrow];
    // fold 1/sqrt(dk) = 0.5 into q
    qv.x *= 0.5f; qv.y *= 0.5f; qv.z *= 0.5f; qv.w *= 0.5f;

    float l = 0.0f;
    float4 acc = make_float4(0.f, 0.f, 0.f, 0.f);
#pragma unroll 8
    for (int k = 0; k < 512; ++k) {
        const float4 kk = kvs[k];            // broadcast LDS read (conflict-free)
        const float s = qv.x * kk.x + qv.y * kk.y + qv.z * kk.z + qv.w * kk.w;
        const float p = __expf(s);           // |s| <= 2, no overflow risk
        l += p;
        acc.x += p * kk.x; acc.y += p * kk.y;
        acc.z += p * kk.z; acc.w += p * kk.w;
    }
    const float inv = 1.0f / l;
    float4 o = make_float4(acc.x * inv, acc.y * inv, acc.z * inv, acc.w * inv);
    *(float4*)(ctx + ((size_t)b * 512 + qrow) * 8 + hh * 4) = o;
}

// ---------------------------------------------------------------------------
// Kernel 2: per-token tail.
// attn_out = qlayer(ctx, attn map); x1 = LN1(attn_out + x);
// hq = x1 @ W_in^T + b_in; q = qlayer(hq, FFN map [0,1,2,2,4,5,6,7]);
// ff = q @ W_out^T + b_out; out = LN2(ff + x1).
// `io` = d_out: reads its own 8 ctx floats, then overwrites them (no races).
// ---------------------------------------------------------------------------
__global__ __launch_bounds__(256) void k_tail(const float* __restrict__ x,
                                              float* io,
                                              const float* __restrict__ tha,
                                              const float* __restrict__ thf,
                                              const float* __restrict__ Win,
                                              const float* __restrict__ bin,
                                              const float* __restrict__ Wout,
                                              const float* __restrict__ bout,
                                              const float* __restrict__ ln1w,
                                              const float* __restrict__ ln1b,
                                              const float* __restrict__ ln2w,
                                              const float* __restrict__ ln2b) {
    const int t = blockIdx.x * 256 + threadIdx.x;   // token index, 65536 total

    const float4* xp = (const float4*)(x + (size_t)t * 8);
    const float4 xa = xp[0], xb = xp[1];
    const float xv[8] = {xa.x, xa.y, xa.z, xa.w, xb.x, xb.y, xb.z, xb.w};

    const float4* cp = (const float4*)(io + (size_t)t * 8);
    const float4 ca = cp[0], cb = cp[1];
    const float cv[8] = {ca.x, ca.y, ca.z, ca.w, cb.x, cb.y, cb.z, cb.w};

    // attn_out = qlayer(ctx) with ATTN wires (identity map)
    float z[8], ao[8];
#pragma unroll
    for (int w = 0; w < 8; ++w) z[w] = cosf(cv[w] + tha[w]);
    zprod8(z, ao);

    // LN1(attn_out + x)
    float y[8];
    float m = 0.f;
#pragma unroll
    for (int i = 0; i < 8; ++i) { y[i] = ao[i] + xv[i]; m += y[i]; }
    m *= 0.125f;
    float v = 0.f;
#pragma unroll
    for (int i = 0; i < 8; ++i) { const float d = y[i] - m; v += d * d; }
    v *= 0.125f;
    float r = rsqrtf(v + 1e-5f);
    float x1[8];
#pragma unroll
    for (int i = 0; i < 8; ++i) x1[i] = (y[i] - m) * r * ln1w[i] + ln1b[i];

    // hq = x1 @ W_in^T + b_in
    float hq[8];
#pragma unroll
    for (int i = 0; i < 8; ++i) {
        float s = bin[i];
#pragma unroll
        for (int j = 0; j < 8; ++j) s += x1[j] * Win[i * 8 + j];
        hq[i] = s;
    }

    // FFN qlayer, wires [0,1,2,2,4,5,6,7]: wire2 gets hq2+hq3, wire3 only theta
    float phi[8];
    phi[0] = hq[0] + thf[0];
    phi[1] = hq[1] + thf[1];
    phi[2] = hq[2] + hq[3] + thf[2];
    phi[3] = thf[3];
    phi[4] = hq[4] + thf[4];
    phi[5] = hq[5] + thf[5];
    phi[6] = hq[6] + thf[6];
    phi[7] = hq[7] + thf[7];
    float qq[8];
#pragma unroll
    for (int w = 0; w < 8; ++w) z[w] = cosf(phi[w]);
    zprod8(z, qq);

    // ff = q @ W_out^T + b_out; y2 = ff + x1; LN2
    float y2[8];
    float m2 = 0.f;
#pragma unroll
    for (int i = 0; i < 8; ++i) {
        float s = bout[i];
#pragma unroll
        for (int j = 0; j < 8; ++j) s += qq[j] * Wout[i * 8 + j];
        y2[i] = s + x1[i];
        m2 += y2[i];
    }
    m2 *= 0.125f;
    float v2 = 0.f;
#pragma unroll
    for (int i = 0; i < 8; ++i) { const float d = y2[i] - m2; v2 += d * d; }
    v2 *= 0.125f;
    const float r2 = rsqrtf(v2 + 1e-5f);

    float o[8];
#pragma unroll
    for (int i = 0; i < 8; ++i) o[i] = (y2[i] - m2) * r2 * ln2w[i] + ln2b[i];

    float4* op = (float4*)(io + (size_t)t * 8);
    op[0] = make_float4(o[0], o[1], o[2], o[3]);
    op[1] = make_float4(o[4], o[5], o[6], o[7]);
}

extern "C" void kernel_launch(void* const* d_in, const int* in_sizes, int n_in,
                              void* d_out, int out_size, void* d_ws, size_t ws_size,
                              hipStream_t stream) {
    const float* x    = (const float*)d_in[0];
    const float* tha  = (const float*)d_in[1];
    const float* thf  = (const float*)d_in[2];
    const float* Win  = (const float*)d_in[3];
    const float* bin  = (const float*)d_in[4];
    const float* Wout = (const float*)d_in[5];
    const float* bout = (const float*)d_in[6];
    const float* ln1w = (const float*)d_in[7];
    const float* ln1b = (const float*)d_in[8];
    const float* ln2w = (const float*)d_in[9];
    const float* ln2b = (const float*)d_in[10];
    float* out = (float*)d_out;

    // B=128, T=512: attention grid = B*heads*qhalves = 128*2*2 = 512
    k_attn<<<512, 256, 0, stream>>>(x, tha, out);
    // tail: 65536 tokens / 256
    k_tail<<<256, 256, 0, stream>>>(x, out, tha, thf, Win, bin, Wout, bout,
                                    ln1w, ln1b, ln2w, ln2b);
}

// Round 3
// 101.795 us; speedup vs baseline: 1.0541x; 1.0541x over previous
//
#include <hip/hip_runtime.h>

// TransformerBlockQuantum — analytic collapse of the 8-qubit qlayer:
// pre-CNOT state is a product of RX rotations => wire w has <Z> = cos(phi_w).
// CNOT ring (k -> k+1 mod 8) maps measurement bits to prefix-XORs:
//   b_w = a_0 ^ ... ^ a_w (w>=1),  b_0 = a_1 ^ ... ^ a_7
// => out[w] = prod_{j<=w} cos(phi_j) (w>=1), out[0] = prod_{j=1..7} cos(phi_j)
// (validated: round-2 kernel passed, absmax 7.8e-3 vs threshold 5.25e-2)

__device__ __forceinline__ void zprod8(const float z[8], float out[8]) {
    float p = z[0];
#pragma unroll
    for (int w = 1; w < 8; ++w) { p *= z[w]; out[w] = p; }
    float q = z[1];
#pragma unroll
    for (int w = 2; w < 8; ++w) q *= z[w];
    out[0] = q;
}

// ---------------------------------------------------------------------------
// Single fused kernel.
// grid = B*2 = 256 blocks, 512 threads (8 waves).
//   blockIdx.x = b*2 + qhalf
//   tid: h = tid>>8 (head, wave-uniform), r = tid&255 (local q-row)
// Phase 1: thread tid stages the full qlayer row `tid` into LDS (no per-head
//          redundancy; 2x per b across the two qhalf blocks).
// Phase 2: thread (h,r) runs softmax-free-max attention for q-row
//          qhalf*256+r, head h (|score|<=2 so exp never overflows).
// Phase 3: ctx halves exchanged through LDS; threads 0..255 run the whole
//          per-token tail (qlayer, LN1, 8x8 GEMV, FFN qlayer, GEMV, LN2).
// ---------------------------------------------------------------------------
__global__ __launch_bounds__(512) void k_fused(const float* __restrict__ x,
                                               const float* __restrict__ tha,
                                               const float* __restrict__ thf,
                                               const float* __restrict__ Win,
                                               const float* __restrict__ bin,
                                               const float* __restrict__ Wout,
                                               const float* __restrict__ bout,
                                               const float* __restrict__ ln1w,
                                               const float* __restrict__ ln1b,
                                               const float* __restrict__ ln2w,
                                               const float* __restrict__ ln2b,
                                               float* __restrict__ out) {
    const int qhalf = blockIdx.x & 1;
    const int b     = blockIdx.x >> 1;
    const int tid   = threadIdx.x;        // 0..511
    const int h     = tid >> 8;           // head, uniform per wave
    const int r     = tid & 255;          // local row

    __shared__ float4 kvs[512][2];        // [row][head], 16 KB

    // ---- Phase 1: stage qlayer(x) rows, one row per thread ----
    {
        const float4* xp = (const float4*)(x + ((size_t)b * 512 + tid) * 8);
        const float4 a  = xp[0];
        const float4 bb = xp[1];
        const float ang[8] = {a.x, a.y, a.z, a.w, bb.x, bb.y, bb.z, bb.w};
        float z[8], o[8];
#pragma unroll
        for (int w = 0; w < 8; ++w) z[w] = __cosf(ang[w] + tha[w]);
        zprod8(z, o);
        kvs[tid][0] = make_float4(o[0], o[1], o[2], o[3]);
        kvs[tid][1] = make_float4(o[4], o[5], o[6], o[7]);
    }
    __syncthreads();

    // ---- Phase 2: attention for (q-row, head) ----
    const int qrow = qhalf * 256 + r;
    float4 qv = kvs[qrow][h];
    // fold 1/sqrt(dk)=0.5 and log2(e) into q; use exp2 (native v_exp_f32)
    const float sc = 0.5f * 1.44269504088896f;
    qv.x *= sc; qv.y *= sc; qv.z *= sc; qv.w *= sc;

    float  l   = 0.0f;
    float4 acc = make_float4(0.f, 0.f, 0.f, 0.f);
#pragma unroll 8
    for (int k = 0; k < 512; ++k) {
        const float4 kk = kvs[k][h];      // wave-uniform addr -> broadcast
        const float s = fmaf(qv.x, kk.x,
                        fmaf(qv.y, kk.y,
                        fmaf(qv.z, kk.z, qv.w * kk.w)));
        const float p = exp2f(s);         // |arg| <= ~2.9
        l += p;
        acc.x = fmaf(p, kk.x, acc.x);
        acc.y = fmaf(p, kk.y, acc.y);
        acc.z = fmaf(p, kk.z, acc.z);
        acc.w = fmaf(p, kk.w, acc.w);
    }
    const float inv = 1.0f / l;
    const float4 cvh = make_float4(acc.x * inv, acc.y * inv,
                                   acc.z * inv, acc.w * inv);

    // ---- Phase 3: exchange ctx halves via LDS (reuse kvs), run tail ----
    __syncthreads();                      // all kvs reads done
    kvs[r][h] = cvh;
    __syncthreads();

    if (tid < 256) {
        const size_t t = (size_t)b * 512 + qhalf * 256 + tid;

        const float4 ca = kvs[tid][0], cb = kvs[tid][1];
        const float cv[8] = {ca.x, ca.y, ca.z, ca.w, cb.x, cb.y, cb.z, cb.w};

        const float4* xp = (const float4*)(x + t * 8);
        const float4 xa = xp[0], xb = xp[1];
        const float xv[8] = {xa.x, xa.y, xa.z, xa.w, xb.x, xb.y, xb.z, xb.w};

        // attn_out = qlayer(ctx), identity wire map
        float z[8], ao[8];
#pragma unroll
        for (int w = 0; w < 8; ++w) z[w] = __cosf(cv[w] + tha[w]);
        zprod8(z, ao);

        // LN1(attn_out + x)
        float y[8], m = 0.f;
#pragma unroll
        for (int i = 0; i < 8; ++i) { y[i] = ao[i] + xv[i]; m += y[i]; }
        m *= 0.125f;
        float v = 0.f;
#pragma unroll
        for (int i = 0; i < 8; ++i) { const float d = y[i] - m; v += d * d; }
        v *= 0.125f;
        const float rs = rsqrtf(v + 1e-5f);
        float x1[8];
#pragma unroll
        for (int i = 0; i < 8; ++i) x1[i] = (y[i] - m) * rs * ln1w[i] + ln1b[i];

        // hq = x1 @ W_in^T + b_in
        float hq[8];
#pragma unroll
        for (int i = 0; i < 8; ++i) {
            float s = bin[i];
#pragma unroll
            for (int j = 0; j < 8; ++j) s = fmaf(x1[j], Win[i * 8 + j], s);
            hq[i] = s;
        }

        // FFN qlayer, wires [0,1,2,2,4,5,6,7]: wire2 <- hq2+hq3, wire3 <- theta only
        float phi[8];
        phi[0] = hq[0] + thf[0];
        phi[1] = hq[1] + thf[1];
        phi[2] = hq[2] + hq[3] + thf[2];
        phi[3] = thf[3];
        phi[4] = hq[4] + thf[4];
        phi[5] = hq[5] + thf[5];
        phi[6] = hq[6] + thf[6];
        phi[7] = hq[7] + thf[7];
        float qq[8];
#pragma unroll
        for (int w = 0; w < 8; ++w) z[w] = __cosf(phi[w]);
        zprod8(z, qq);

        // ff = qq @ W_out^T + b_out; y2 = ff + x1; LN2
        float y2[8], m2 = 0.f;
#pragma unroll
        for (int i = 0; i < 8; ++i) {
            float s = bout[i];
#pragma unroll
            for (int j = 0; j < 8; ++j) s = fmaf(qq[j], Wout[i * 8 + j], s);
            y2[i] = s + x1[i];
            m2 += y2[i];
        }
        m2 *= 0.125f;
        float v2 = 0.f;
#pragma unroll
        for (int i = 0; i < 8; ++i) { const float d = y2[i] - m2; v2 += d * d; }
        v2 *= 0.125f;
        const float r2 = rsqrtf(v2 + 1e-5f);

        float o[8];
#pragma unroll
        for (int i = 0; i < 8; ++i) o[i] = (y2[i] - m2) * r2 * ln2w[i] + ln2b[i];

        float4* op = (float4*)(out + t * 8);
        op[0] = make_float4(o[0], o[1], o[2], o[3]);
        op[1] = make_float4(o[4], o[5], o[6], o[7]);
    }
}

extern "C" void kernel_launch(void* const* d_in, const int* in_sizes, int n_in,
                              void* d_out, int out_size, void* d_ws, size_t ws_size,
                              hipStream_t stream) {
    const float* x    = (const float*)d_in[0];
    const float* tha  = (const float*)d_in[1];
    const float* thf  = (const float*)d_in[2];
    const float* Win  = (const float*)d_in[3];
    const float* bin  = (const float*)d_in[4];
    const float* Wout = (const float*)d_in[5];
    const float* bout = (const float*)d_in[6];
    const float* ln1w = (const float*)d_in[7];
    const float* ln1b = (const float*)d_in[8];
    const float* ln2w = (const float*)d_in[9];
    const float* ln2b = (const float*)d_in[10];
    float* out = (float*)d_out;

    // B=128: grid = B * 2 qhalves = 256 blocks x 512 threads
    k_fused<<<256, 512, 0, stream>>>(x, tha, thf, Win, bin, Wout, bout,
                                     ln1w, ln1b, ln2w, ln2b, out);
}

// Round 5
// 94.934 us; speedup vs baseline: 1.1303x; 1.0723x over previous
//
#include <hip/hip_runtime.h>

// TransformerBlockQuantum — analytic collapse of the 8-qubit qlayer:
// pre-CNOT state is a product of RX rotations => wire w has <Z> = cos(phi_w).
// CNOT ring (k -> k+1 mod 8) maps measurement bits to prefix-XORs:
//   b_w = a_0 ^ ... ^ a_w (w>=1),  b_0 = a_1 ^ ... ^ a_7
// => out[w] = prod_{j<=w} cos(phi_j) (w>=1), out[0] = prod_{j=1..7} cos(phi_j)
// (validated: rounds 2/3 passed, absmax 7.8e-3 vs threshold 5.25e-2)

__device__ __forceinline__ void zprod8(const float z[8], float out[8]) {
    float p = z[0];
#pragma unroll
    for (int w = 1; w < 8; ++w) { p *= z[w]; out[w] = p; }
    float q = z[1];
#pragma unroll
    for (int w = 2; w < 8; ++w) q *= z[w];
    out[0] = q;
}

// ---------------------------------------------------------------------------
// Single fused kernel.
// grid = B*2 = 256 blocks, 512 threads (8 waves).
//   blockIdx.x = b*2 + qhalf
//   tid: h = tid>>8 (head, wave-uniform), r = tid&255 (local q-row)
// Phase 1: thread tid stages the full qlayer row `tid` into LDS.
// Phase 2: thread (h,r) runs max-free softmax attention for q-row
//          qhalf*256+r, head h (|score*log2e| <= 2.9, exp2 never overflows).
// Phase 3: ctx halves exchanged through LDS; threads 0..255 run the whole
//          per-token tail (qlayer, LN1, 8x8 GEMV, FFN qlayer, GEMV, LN2).
// Hot-loop exp is __builtin_amdgcn_exp2f -> single v_exp_f32 (the precise
// exp2f OCML path costs ~8 extra VALU per iter in a 512-iter loop).
// ---------------------------------------------------------------------------
__global__ __launch_bounds__(512) void k_fused(const float* __restrict__ x,
                                               const float* __restrict__ tha,
                                               const float* __restrict__ thf,
                                               const float* __restrict__ Win,
                                               const float* __restrict__ bin,
                                               const float* __restrict__ Wout,
                                               const float* __restrict__ bout,
                                               const float* __restrict__ ln1w,
                                               const float* __restrict__ ln1b,
                                               const float* __restrict__ ln2w,
                                               const float* __restrict__ ln2b,
                                               float* __restrict__ out) {
    const int qhalf = blockIdx.x & 1;
    const int b     = blockIdx.x >> 1;
    const int tid   = threadIdx.x;        // 0..511
    const int h     = tid >> 8;           // head, uniform per wave
    const int r     = tid & 255;          // local row

    __shared__ float4 kvs[512][2];        // [row][head], 16 KB

    // ---- Phase 1: stage qlayer(x) rows, one row per thread ----
    {
        const float4* xp = (const float4*)(x + ((size_t)b * 512 + tid) * 8);
        const float4 a  = xp[0];
        const float4 bb = xp[1];
        const float ang[8] = {a.x, a.y, a.z, a.w, bb.x, bb.y, bb.z, bb.w};
        float z[8], o[8];
#pragma unroll
        for (int w = 0; w < 8; ++w) z[w] = __cosf(ang[w] + tha[w]);
        zprod8(z, o);
        kvs[tid][0] = make_float4(o[0], o[1], o[2], o[3]);
        kvs[tid][1] = make_float4(o[4], o[5], o[6], o[7]);
    }
    __syncthreads();

    // ---- Phase 2: attention for (q-row, head) ----
    const int qrow = qhalf * 256 + r;
    float4 qv = kvs[qrow][h];
    // fold 1/sqrt(dk)=0.5 and log2(e) into q; exp2 via native v_exp_f32
    const float sc = 0.5f * 1.44269504088896f;
    qv.x *= sc; qv.y *= sc; qv.z *= sc; qv.w *= sc;

    float  l   = 0.0f;
    float4 acc = make_float4(0.f, 0.f, 0.f, 0.f);
#pragma unroll 8
    for (int k = 0; k < 512; ++k) {
        const float4 kk = kvs[k][h];      // wave-uniform addr -> broadcast
        const float s = fmaf(qv.x, kk.x,
                        fmaf(qv.y, kk.y,
                        fmaf(qv.z, kk.z, qv.w * kk.w)));
        const float p = __builtin_amdgcn_exp2f(s);   // v_exp_f32, |s|<=2.9
        l += p;
        acc.x = fmaf(p, kk.x, acc.x);
        acc.y = fmaf(p, kk.y, acc.y);
        acc.z = fmaf(p, kk.z, acc.z);
        acc.w = fmaf(p, kk.w, acc.w);
    }
    const float inv = 1.0f / l;
    const float4 cvh = make_float4(acc.x * inv, acc.y * inv,
                                   acc.z * inv, acc.w * inv);

    // ---- Phase 3: exchange ctx halves via LDS (reuse kvs), run tail ----
    __syncthreads();                      // all kvs reads done
    kvs[r][h] = cvh;
    __syncthreads();

    if (tid < 256) {
        const size_t t = (size_t)b * 512 + qhalf * 256 + tid;

        const float4 ca = kvs[tid][0], cb = kvs[tid][1];
        const float cv[8] = {ca.x, ca.y, ca.z, ca.w, cb.x, cb.y, cb.z, cb.w};

        const float4* xp = (const float4*)(x + t * 8);
        const float4 xa = xp[0], xb = xp[1];
        const float xv[8] = {xa.x, xa.y, xa.z, xa.w, xb.x, xb.y, xb.z, xb.w};

        // attn_out = qlayer(ctx), identity wire map
        float z[8], ao[8];
#pragma unroll
        for (int w = 0; w < 8; ++w) z[w] = __cosf(cv[w] + tha[w]);
        zprod8(z, ao);

        // LN1(attn_out + x)
        float y[8], m = 0.f;
#pragma unroll
        for (int i = 0; i < 8; ++i) { y[i] = ao[i] + xv[i]; m += y[i]; }
        m *= 0.125f;
        float v = 0.f;
#pragma unroll
        for (int i = 0; i < 8; ++i) { const float d = y[i] - m; v += d * d; }
        v *= 0.125f;
        const float rs = rsqrtf(v + 1e-5f);
        float x1[8];
#pragma unroll
        for (int i = 0; i < 8; ++i) x1[i] = (y[i] - m) * rs * ln1w[i] + ln1b[i];

        // hq = x1 @ W_in^T + b_in
        float hq[8];
#pragma unroll
        for (int i = 0; i < 8; ++i) {
            float s = bin[i];
#pragma unroll
            for (int j = 0; j < 8; ++j) s = fmaf(x1[j], Win[i * 8 + j], s);
            hq[i] = s;
        }

        // FFN qlayer, wires [0,1,2,2,4,5,6,7]: wire2 <- hq2+hq3, wire3 <- theta only
        float phi[8];
        phi[0] = hq[0] + thf[0];
        phi[1] = hq[1] + thf[1];
        phi[2] = hq[2] + hq[3] + thf[2];
        phi[3] = thf[3];
        phi[4] = hq[4] + thf[4];
        phi[5] = hq[5] + thf[5];
        phi[6] = hq[6] + thf[6];
        phi[7] = hq[7] + thf[7];
        float qq[8];
#pragma unroll
        for (int w = 0; w < 8; ++w) z[w] = __cosf(phi[w]);
        zprod8(z, qq);

        // ff = qq @ W_out^T + b_out; y2 = ff + x1; LN2
        float y2[8], m2 = 0.f;
#pragma unroll
        for (int i = 0; i < 8; ++i) {
            float s = bout[i];
#pragma unroll
            for (int j = 0; j < 8; ++j) s = fmaf(qq[j], Wout[i * 8 + j], s);
            y2[i] = s + x1[i];
            m2 += y2[i];
        }
        m2 *= 0.125f;
        float v2 = 0.f;
#pragma unroll
        for (int i = 0; i < 8; ++i) { const float d = y2[i] - m2; v2 += d * d; }
        v2 *= 0.125f;
        const float r2 = rsqrtf(v2 + 1e-5f);

        float o[8];
#pragma unroll
        for (int i = 0; i < 8; ++i) o[i] = (y2[i] - m2) * r2 * ln2w[i] + ln2b[i];

        float4* op = (float4*)(out + t * 8);
        op[0] = make_float4(o[0], o[1], o[2], o[3]);
        op[1] = make_float4(o[4], o[5], o[6], o[7]);
    }
}

extern "C" void kernel_launch(void* const* d_in, const int* in_sizes, int n_in,
                              void* d_out, int out_size, void* d_ws, size_t ws_size,
                              hipStream_t stream) {
    const float* x    = (const float*)d_in[0];
    const float* tha  = (const float*)d_in[1];
    const float* thf  = (const float*)d_in[2];
    const float* Win  = (const float*)d_in[3];
    const float* bin  = (const float*)d_in[4];
    const float* Wout = (const float*)d_in[5];
    const float* bout = (const float*)d_in[6];
    const float* ln1w = (const float*)d_in[7];
    const float* ln1b = (const float*)d_in[8];
    const float* ln2w = (const float*)d_in[9];
    const float* ln2b = (const float*)d_in[10];
    float* out = (float*)d_out;

    // B=128: grid = B * 2 qhalves = 256 blocks x 512 threads
    k_fused<<<256, 512, 0, stream>>>(x, tha, thf, Win, bin, Wout, bout,
                                     ln1w, ln1b, ln2w, ln2b, out);
}

// Round 6
// 93.274 us; speedup vs baseline: 1.1504x; 1.0178x over previous
//
#include <hip/hip_runtime.h>

// TransformerBlockQuantum — analytic collapse of the 8-qubit qlayer:
// pre-CNOT state is a product of RX rotations => wire w has <Z> = cos(phi_w).
// CNOT ring (k -> k+1 mod 8) maps measurement bits to prefix-XORs:
//   b_w = a_0 ^ ... ^ a_w (w>=1),  b_0 = a_1 ^ ... ^ a_7
// => out[w] = prod_{j<=w} cos(phi_j) (w>=1), out[0] = prod_{j=1..7} cos(phi_j)
// (validated: rounds 2/3/5 passed, absmax 7.8e-3 vs threshold 5.25e-2)
//
// Round 6: packed-fp32 hot loop. v_pk_fma_f32/v_pk_mul_f32/v_pk_add_f32
// (VOP3P, full-rate on CDNA) process 2 K-rows per issue slot. K/V staged in
// SoA-pair layout so one ds_read_b128 yields {c(2s),c(2s+1)} component pairs.

typedef float v2f __attribute__((ext_vector_type(2)));

__device__ __forceinline__ v2f pk_fma(v2f a, v2f b, v2f c) {
    v2f d;
    asm("v_pk_fma_f32 %0, %1, %2, %3" : "=v"(d) : "v"(a), "v"(b), "v"(c));
    return d;
}
__device__ __forceinline__ v2f pk_mul(v2f a, v2f b) {
    v2f d;
    asm("v_pk_mul_f32 %0, %1, %2" : "=v"(d) : "v"(a), "v"(b));
    return d;
}
__device__ __forceinline__ v2f pk_add(v2f a, v2f b) {
    v2f d;
    asm("v_pk_add_f32 %0, %1, %2" : "=v"(d) : "v"(a), "v"(b));
    return d;
}

__device__ __forceinline__ void zprod8(const float z[8], float out[8]) {
    float p = z[0];
#pragma unroll
    for (int w = 1; w < 8; ++w) { p *= z[w]; out[w] = p; }
    float q = z[1];
#pragma unroll
    for (int w = 2; w < 8; ++w) q *= z[w];
    out[0] = q;
}

// ---------------------------------------------------------------------------
// Single fused kernel. grid = B*2 = 256 blocks, 512 threads (8 waves).
//   blockIdx.x = b*2 + qhalf; h = tid>>8 (head, wave-uniform), r = tid&255.
// Phase 1: thread tid computes qlayer row tid, scatters it into SoA-pair LDS:
//   A[h][s] = {kx(2s),kx(2s+1),ky(2s),ky(2s+1)}, Bv[h][s] = {kz.., kw..}
// Phase 2: thread (h,r) runs max-free softmax attention for q-row
//   qhalf*256+r over 256 packed iterations (2 rows each).
// Phase 3: ctx exchanged via separate LDS buffer; threads 0..255 run the tail.
// ---------------------------------------------------------------------------
__global__ __launch_bounds__(512) void k_fused(const float* __restrict__ x,
                                               const float* __restrict__ tha,
                                               const float* __restrict__ thf,
                                               const float* __restrict__ Win,
                                               const float* __restrict__ bin,
                                               const float* __restrict__ Wout,
                                               const float* __restrict__ bout,
                                               const float* __restrict__ ln1w,
                                               const float* __restrict__ ln1b,
                                               const float* __restrict__ ln2w,
                                               const float* __restrict__ ln2b,
                                               float* __restrict__ out) {
    const int qhalf = blockIdx.x & 1;
    const int b     = blockIdx.x >> 1;
    const int tid   = threadIdx.x;        // 0..511
    const int h     = tid >> 8;           // head, uniform per wave
    const int r     = tid & 255;          // local q-row

    __shared__ float4 A[2][256];          // [head][slot] {kx_e,kx_o,ky_e,ky_o}
    __shared__ float4 Bv[2][256];         // [head][slot] {kz_e,kz_o,kw_e,kw_o}
    __shared__ float4 ctxs[256][2];       // ctx exchange [row][head]

    // ---- Phase 1: stage qlayer(x) rows into SoA-pair layout ----
    {
        const float4* xp = (const float4*)(x + ((size_t)b * 512 + tid) * 8);
        const float4 a  = xp[0];
        const float4 bb = xp[1];
        const float ang[8] = {a.x, a.y, a.z, a.w, bb.x, bb.y, bb.z, bb.w};
        float z[8], o[8];
#pragma unroll
        for (int w = 0; w < 8; ++w) z[w] = __cosf(ang[w] + tha[w]);
        zprod8(z, o);
        const int s   = tid >> 1;
        const int par = tid & 1;
        float* a0 = (float*)&A[0][s];
        a0[par] = o[0]; a0[2 + par] = o[1];
        float* b0 = (float*)&Bv[0][s];
        b0[par] = o[2]; b0[2 + par] = o[3];
        float* a1 = (float*)&A[1][s];
        a1[par] = o[4]; a1[2 + par] = o[5];
        float* b1 = (float*)&Bv[1][s];
        b1[par] = o[6]; b1[2 + par] = o[7];
    }
    __syncthreads();

    // ---- Phase 2: packed attention for (q-row, head) ----
    const int qrow = qhalf * 256 + r;
    const float4 qa = A[h][qrow >> 1];
    const float4 qb = Bv[h][qrow >> 1];
    const int qp = qrow & 1;
    // fold 1/sqrt(dk)=0.5 and log2(e); exp via native v_exp_f32
    const float sc = 0.5f * 1.44269504088896f;
    const float qx = (qp ? qa.y : qa.x) * sc;
    const float qy = (qp ? qa.w : qa.z) * sc;
    const float qz = (qp ? qb.y : qb.x) * sc;
    const float qw = (qp ? qb.w : qb.z) * sc;
    const v2f qx2 = {qx, qx}, qy2 = {qy, qy}, qz2 = {qz, qz}, qw2 = {qw, qw};

    v2f l2  = {0.f, 0.f};
    v2f ax2 = {0.f, 0.f}, ay2 = {0.f, 0.f}, az2 = {0.f, 0.f}, aw2 = {0.f, 0.f};
    const float4* pA = A[h];
    const float4* pB = Bv[h];
#pragma unroll 8
    for (int j = 0; j < 256; ++j) {
        const float4 ab = pA[j];          // wave-uniform addr -> broadcast
        const float4 cd = pB[j];
        const v2f kx2 = {ab.x, ab.y}, ky2 = {ab.z, ab.w};
        const v2f kz2 = {cd.x, cd.y}, kw2 = {cd.z, cd.w};
        v2f s2 = pk_mul(qw2, kw2);
        s2 = pk_fma(qz2, kz2, s2);
        s2 = pk_fma(qy2, ky2, s2);
        s2 = pk_fma(qx2, kx2, s2);        // |s2| <= 2.89
        v2f p2;
        p2.x = __builtin_amdgcn_exp2f(s2.x);
        p2.y = __builtin_amdgcn_exp2f(s2.y);
        l2  = pk_add(l2, p2);
        ax2 = pk_fma(p2, kx2, ax2);
        ay2 = pk_fma(p2, ky2, ay2);
        az2 = pk_fma(p2, kz2, az2);
        aw2 = pk_fma(p2, kw2, aw2);
    }
    const float inv = 1.0f / (l2.x + l2.y);
    const float4 cvh = make_float4((ax2.x + ax2.y) * inv, (ay2.x + ay2.y) * inv,
                                   (az2.x + az2.y) * inv, (aw2.x + aw2.y) * inv);

    // ---- Phase 3: exchange ctx via dedicated LDS (no aliasing), run tail ----
    ctxs[r][h] = cvh;
    __syncthreads();

    if (tid < 256) {
        const size_t t = (size_t)b * 512 + qhalf * 256 + tid;

        const float4 ca = ctxs[tid][0], cb = ctxs[tid][1];
        const float cv[8] = {ca.x, ca.y, ca.z, ca.w, cb.x, cb.y, cb.z, cb.w};

        const float4* xp = (const float4*)(x + t * 8);
        const float4 xa = xp[0], xb = xp[1];
        const float xv[8] = {xa.x, xa.y, xa.z, xa.w, xb.x, xb.y, xb.z, xb.w};

        // attn_out = qlayer(ctx), identity wire map
        float z[8], ao[8];
#pragma unroll
        for (int w = 0; w < 8; ++w) z[w] = __cosf(cv[w] + tha[w]);
        zprod8(z, ao);

        // LN1(attn_out + x)
        float y[8], m = 0.f;
#pragma unroll
        for (int i = 0; i < 8; ++i) { y[i] = ao[i] + xv[i]; m += y[i]; }
        m *= 0.125f;
        float v = 0.f;
#pragma unroll
        for (int i = 0; i < 8; ++i) { const float d = y[i] - m; v += d * d; }
        v *= 0.125f;
        const float rs = rsqrtf(v + 1e-5f);
        float x1[8];
#pragma unroll
        for (int i = 0; i < 8; ++i) x1[i] = (y[i] - m) * rs * ln1w[i] + ln1b[i];

        // hq = x1 @ W_in^T + b_in
        float hq[8];
#pragma unroll
        for (int i = 0; i < 8; ++i) {
            float s = bin[i];
#pragma unroll
            for (int j = 0; j < 8; ++j) s = fmaf(x1[j], Win[i * 8 + j], s);
            hq[i] = s;
        }

        // FFN qlayer, wires [0,1,2,2,4,5,6,7]: wire2 <- hq2+hq3, wire3 <- theta
        float phi[8];
        phi[0] = hq[0] + thf[0];
        phi[1] = hq[1] + thf[1];
        phi[2] = hq[2] + hq[3] + thf[2];
        phi[3] = thf[3];
        phi[4] = hq[4] + thf[4];
        phi[5] = hq[5] + thf[5];
        phi[6] = hq[6] + thf[6];
        phi[7] = hq[7] + thf[7];
        float qq[8];
#pragma unroll
        for (int w = 0; w < 8; ++w) z[w] = __cosf(phi[w]);
        zprod8(z, qq);

        // ff = qq @ W_out^T + b_out; y2 = ff + x1; LN2
        float y2[8], m2 = 0.f;
#pragma unroll
        for (int i = 0; i < 8; ++i) {
            float s = bout[i];
#pragma unroll
            for (int j = 0; j < 8; ++j) s = fmaf(qq[j], Wout[i * 8 + j], s);
            y2[i] = s + x1[i];
            m2 += y2[i];
        }
        m2 *= 0.125f;
        float v2 = 0.f;
#pragma unroll
        for (int i = 0; i < 8; ++i) { const float d = y2[i] - m2; v2 += d * d; }
        v2 *= 0.125f;
        const float r2 = rsqrtf(v2 + 1e-5f);

        float o[8];
#pragma unroll
        for (int i = 0; i < 8; ++i) o[i] = (y2[i] - m2) * r2 * ln2w[i] + ln2b[i];

        float4* op = (float4*)(out + t * 8);
        op[0] = make_float4(o[0], o[1], o[2], o[3]);
        op[1] = make_float4(o[4], o[5], o[6], o[7]);
    }
}

extern "C" void kernel_launch(void* const* d_in, const int* in_sizes, int n_in,
                              void* d_out, int out_size, void* d_ws, size_t ws_size,
                              hipStream_t stream) {
    const float* x    = (const float*)d_in[0];
    const float* tha  = (const float*)d_in[1];
    const float* thf  = (const float*)d_in[2];
    const float* Win  = (const float*)d_in[3];
    const float* bin  = (const float*)d_in[4];
    const float* Wout = (const float*)d_in[5];
    const float* bout = (const float*)d_in[6];
    const float* ln1w = (const float*)d_in[7];
    const float* ln1b = (const float*)d_in[8];
    const float* ln2w = (const float*)d_in[9];
    const float* ln2b = (const float*)d_in[10];
    float* out = (float*)d_out;

    // B=128: grid = B * 2 qhalves = 256 blocks x 512 threads
    k_fused<<<256, 512, 0, stream>>>(x, tha, thf, Win, bin, Wout, bout,
                                     ln1w, ln1b, ln2w, ln2b, out);
}